// Round 17
// baseline (181.626 us; speedup 1.0000x reference)
//
#include <hip/hip_runtime.h>
#include <math.h>

// Problem constants
#define BDIM 4
#define GDIM 40
#define CDIM 13
#define TDIM 1024
#define FDIM 513                 // T/2 + 1
#define BG   (BDIM*GDIM)         // 160
#define NROW (BG*FDIM)           // 82080 rows of [13] complex
#define NCHUNK 9                 // 9*64 = 576 >= 513 q-rows per bg (qkv)
#define NPAIR 5                  // attn: 5 chunk-pairs of 128 q-rows per bg
#define TK 64                    // K rows staged per LDS tile (attn)
#define QW 64                    // f-rows per qkv block

typedef _Float16 half4 __attribute__((ext_vector_type(4)));
typedef _Float16 half8 __attribute__((ext_vector_type(8)));
typedef float    f32x4 __attribute__((ext_vector_type(4)));

#define MFMA16(a, b, c) __builtin_amdgcn_mfma_f32_16x16x16f16((a), (b), (c), 0, 0, 0)

__device__ __forceinline__ unsigned bitrev10(unsigned x) { return __brev(x) >> 22; }

// padded LDS index: breaks stride-4h bank conflicts in the radix-4 rounds
#define IDX(i) ((i) + ((i) >> 5))

// ---------------- Kernel 1: two-for-one rfft(1024), radix-4 fused ----------------
// 256 threads; 5 fused rounds; barriers 10 -> 5. xf signal-major [sig=bg*13+c][f].
// (r14/r15 verified: coalesced writes + radix-4 = others 98.7 -> 83.4 us)
__global__ __launch_bounds__(256) void fft_fwd2(const float* __restrict__ x,
                                                float2* __restrict__ xf) {
    __shared__ float re[1056], im[1056];
    const int s2 = blockIdx.x;                   // pair index, 0..1039
    const int sigA = 2 * s2, sigB = sigA + 1;
    const float* x1 = x + (size_t)sigA * TDIM;
    const float* x2 = x1 + TDIM;
    for (int t = threadIdx.x; t < 1024; t += 256) {
        unsigned r = bitrev10(t);
        re[IDX(r)] = x1[t];
        im[IDX(r)] = x2[t];
    }
    __syncthreads();
    for (int s = 0; s < 10; s += 2) {            // fused stage pair (s, s+1)
        const int h   = 1 << s;
        const int g   = threadIdx.x;             // 256 groups of 4 points
        const int grp = g >> s;
        const int pos = g & (h - 1);
        const int i0  = (grp << (s + 2)) + pos;
        const int j0 = IDX(i0), j1 = IDX(i0 + h), j2 = IDX(i0 + 2 * h), j3 = IDX(i0 + 3 * h);
        float w1s, w1c, w2s, w2c;
        __sincosf(-(float)M_PI * (float)pos / (float)h, &w1s, &w1c);
        __sincosf(-(float)M_PI * (float)pos / (float)(2 * h), &w2s, &w2c);
        float ar = re[j0], ai = im[j0], br = re[j1], bi = im[j1];
        float cr = re[j2], ci = im[j2], dr = re[j3], di = im[j3];
        float t1;
        t1 = w1c * br - w1s * bi; bi = w1c * bi + w1s * br; br = t1;   // B *= w1
        t1 = w1c * dr - w1s * di; di = w1c * di + w1s * dr; dr = t1;   // D *= w1
        float e0r = ar + br, e0i = ai + bi, e1r = ar - br, e1i = ai - bi;
        float f0r = cr + dr, f0i = ci + di, f1r = cr - dr, f1i = ci - di;
        t1 = w2c * f0r - w2s * f0i; f0i = w2c * f0i + w2s * f0r; f0r = t1;   // *= w2
        // w3 = -i*w2 = (w2s, -w2c)
        t1 = w2s * f1r + w2c * f1i; f1i = w2s * f1i - w2c * f1r; f1r = t1;   // *= w3
        re[j0] = e0r + f0r; im[j0] = e0i + f0i;
        re[j2] = e0r - f0r; im[j2] = e0i - f0i;
        re[j1] = e1r + f1r; im[j1] = e1i + f1i;
        re[j3] = e1r - f1r; im[j3] = e1i - f1i;
        __syncthreads();
    }
    for (int f = threadIdx.x; f < FDIM; f += 256) {
        int fr = (1024 - f) & 1023;
        float zr = re[IDX(f)], zi = im[IDX(f)];
        float wr = re[IDX(fr)], wi = im[IDX(fr)];
        xf[(size_t)sigA * FDIM + f] =
            make_float2(0.5f * (zr + wr), 0.5f * (zi - wi));     // coalesced
        xf[(size_t)sigB * FDIM + f] =
            make_float2(0.5f * (zi + wi), 0.5f * (wr - zr));
    }
}

// ---------------- Kernel 2: Q/K/V projections (coalesced both sides, XCD-pinned) ----------------
__global__ __launch_bounds__(256) void qkv_kernel(const float2* __restrict__ xf,
                           const float* __restrict__ wq,
                           const float* __restrict__ wk,
                           const float* __restrict__ wv,
                           float2* __restrict__ q,
                           _Float16* __restrict__ KP,
                           _Float16* __restrict__ VT) {
    __shared__ float2   Xs[QW * CDIM];           // staged xf rows, [row][c]
    __shared__ float    Ws[3 * CDIM * CDIM];     // wq | wk | wv
    __shared__ _Float16 KPs[QW * 72];            // KP tile, padded stride
    __shared__ _Float16 VTs[32 * 72];            // VT tile (pc = part*16+c, j), padded

    const int bg    = blockIdx.x % BG;           // XCD-pinned
    const int ch    = blockIdx.x / BG;
    const int f0    = ch * QW;
    const int nrows = min(QW, FDIM - f0);        // 64, or 1 for ch==8
    const int tid   = threadIdx.x;
    const int nitems = nrows * CDIM;

    for (int idx = tid; idx < nitems; idx += 256) {
        int c   = idx / nrows;
        int row = idx - c * nrows;
        Xs[row * CDIM + c] = xf[((size_t)bg * CDIM + c) * FDIM + f0 + row];
    }
    for (int idx = tid; idx < 3 * 169; idx += 256)
        Ws[idx] = (idx < 169) ? wq[idx] : ((idx < 338) ? wk[idx - 169] : wv[idx - 338]);
    for (int z = tid; z < 6 * QW; z += 256) {    // zero VT pad c-rows
        int rr = z >> 6, jj = z & 63;
        int pc = (rr < 3) ? (13 + rr) : (29 + (rr - 3));
        VTs[pc * 72 + jj] = (_Float16)0.f;
    }
    __syncthreads();

    for (int item = tid; item < nitems; item += 256) {
        int row = item / CDIM;
        int i   = item - row * CDIM;
        const float2* xrow = &Xs[row * CDIM];
        float qr = 0, qi = 0, kr = 0, ki = 0, vr = 0, vi = 0;
#pragma unroll
        for (int c = 0; c < CDIM; ++c) {
            float2 xc = xrow[c];
            float a = Ws[c * CDIM + i];       qr += xc.x * a; qi += xc.y * a;
            float b = Ws[169 + c * CDIM + i]; kr += xc.x * b; ki += xc.y * b;
            float d = Ws[338 + c * CDIM + i]; vr += xc.x * d; vi += xc.y * d;
        }
        q[((size_t)bg * FDIM + f0) * CDIM + item] = make_float2(qr, qi);  // coalesced
        _Float16* kp = KPs + row * 72;
        _Float16 h0 = (_Float16)kr, h1 = (_Float16)ki;
        kp[i]      = h0;
        kp[13 + i] = h1;
        kp[32 + i] = (_Float16)(kr - (float)h0);
        kp[45 + i] = (_Float16)(ki - (float)h1);
        if (i == 12) {   // zero pad halves 26..31 and 58..63
            *(unsigned*)(kp + 26) = 0u; *(unsigned*)(kp + 28) = 0u; *(unsigned*)(kp + 30) = 0u;
            *(unsigned*)(kp + 58) = 0u; *(unsigned*)(kp + 60) = 0u; *(unsigned*)(kp + 62) = 0u;
        }
        VTs[i * 72 + row]        = (_Float16)vr;   // part 0, c = i
        VTs[(16 + i) * 72 + row] = (_Float16)vi;   // part 1
    }
    __syncthreads();

    _Float16* KPg = KP + ((size_t)bg * FDIM + f0) * 64;
    _Float16* VTg = VT + (size_t)bg * 2 * 16 * 520 + f0;
    if (nrows == QW) {
        for (int idx = tid; idx < QW * 8; idx += 256) {        // 512 x 16B
            int row = idx >> 3, gg = idx & 7;
            *(half8*)(KPg + row * 64 + gg * 8) = *(const half8*)(KPs + row * 72 + gg * 8);
        }
        for (int idx = tid; idx < 32 * 8; idx += 256) {        // 256 x 16B
            int pc = idx >> 3, j8 = idx & 7;
            *(half8*)(VTg + pc * 520 + j8 * 8) = *(const half8*)(VTs + pc * 72 + j8 * 8);
        }
    } else {   // tail chunk: nrows == 1 (f == 512)
        for (int idx = tid; idx < nrows * 8; idx += 256) {
            int row = idx >> 3, gg = idx & 7;
            *(half8*)(KPg + row * 64 + gg * 8) = *(const half8*)(KPs + row * 72 + gg * 8);
        }
        if (tid < 32) VTg[tid * 520] = VTs[tid * 72];
    }
}

// ---------------- Kernel 3: MFMA flash attention (2 q-sets/wave, 128 rows/block) ----------------
// r17: r16 structure (grid 800, each staged tile feeds 2 q-sets -> staging/barriers
// -44%, conflicts halved to 2.76M measured) with __launch_bounds__(256, 3).
// r16's ONLY failure was register allocation: at (256,4) the allocator pinned VGPR
// at the 64 tier and spilled ~40 regs (WRITE 8.6->22.6MB, 107us). ALLOCATOR RULE
// (r3/r6/r16, three data points): hipcc targets the tier boundary implied by the
// min-waves bound, NOT the declared cap — give it the 3-waves/EU tier (~170 cap)
// and it lands at actual need (r4: picked 60 when 60 needed). 3 blocks/CU x 256CU
// = 768 ~= grid 800; 12 waves/CU = same occupancy regime as every working variant.
// HISTORY: no-LDS = 113us (r8); prefetch flat (r9/r10); bg-fused -7us (r12);
// XCD pinning: FETCH 68.4->13.3MB, +5us (r15). r15 1-set fingerprint: 76.2us,
// VGPR 52, MfmaUtil 32. Pre-commit: VGPR<=70 or WRITE>12MB here -> revert to r15.
__global__ __launch_bounds__(256, 3) void attn_kernel(const float2* __restrict__ q,
                                                      const _Float16* __restrict__ KP,
                                                      const _Float16* __restrict__ VT,
                                                      float2* __restrict__ outspec) {
    __shared__ __align__(16) _Float16 Klds[TK * 64];        // 8 KB, XOR-swizzled 16B granules
    __shared__ __align__(16) _Float16 VTlds[2 * 16 * 72];   // 4.6 KB, c-stride 72 halves

    const int bg    = blockIdx.x % BG;           // XCD-pinned (800 = 5*160, 160%8==0)
    const int pr    = blockIdx.x / BG;           // chunk-pair 0..4
    const int tid   = threadIdx.x;
    const int w     = tid >> 6;
    const int lane  = tid & 63;
    const int qlane = lane & 15;
    const int g     = lane >> 4;

    // ---- build Q fragments for both q-sets: u = [qr,-qi], u' = [qi,qr], hi/lo ----
    half4 uh[2][2], ul[2][2], u2h[2][2], u2l[2][2];
    int   frow_s[2];
#pragma unroll
    for (int s = 0; s < 2; ++s) {
        frow_s[s] = (2 * pr + s) * 64 + w * 16 + qlane;
        const int f = (frow_s[s] < FDIM) ? frow_s[s] : (FDIM - 1);
        const size_t rowbase = ((size_t)bg * FDIM + f) * CDIM;
#pragma unroll
        for (int c01 = 0; c01 < 2; ++c01) {
#pragma unroll
            for (int j = 0; j < 4; ++j) {
                int k = c01 * 16 + 4 * g + j;
                float a = 0.f, b = 0.f;
                if (k < CDIM) {
                    float2 t = q[rowbase + k];          a = t.x;  b = t.y;
                } else if (k < 2 * CDIM) {
                    float2 t = q[rowbase + (k - CDIM)]; a = -t.y; b = t.x;
                }
                _Float16 ah = (_Float16)a;
                uh[s][c01][j]  = ah;
                ul[s][c01][j]  = (_Float16)(a - (float)ah);
                _Float16 bh = (_Float16)b;
                u2h[s][c01][j] = bh;
                u2l[s][c01][j] = (_Float16)(b - (float)bh);
            }
        }
    }

    f32x4 o_re[2], o_im[2];
    float m[2], l[2];
#pragma unroll
    for (int s = 0; s < 2; ++s) {
        o_re[s] = (f32x4){0.f, 0.f, 0.f, 0.f};
        o_im[s] = (f32x4){0.f, 0.f, 0.f, 0.f};
        m[s] = -INFINITY; l[s] = 0.f;
    }

    const _Float16* __restrict__ KPg = KP + (size_t)bg * FDIM * 64;
    const _Float16* __restrict__ VTg = VT + (size_t)bg * 2 * 16 * 520;

    for (int t0 = 0; t0 < FDIM; t0 += TK) {          // 9 tiles of 64 K-rows
        __syncthreads();                             // previous tile fully consumed
        // ---- stage K rows (2 x 16B granules per thread, XOR-swizzled placement) ----
#pragma unroll
        for (int hh = 0; hh < 2; ++hh) {
            int gr  = tid + hh * 256;                // 0..511
            int krw = gr >> 3, gg = gr & 7;
            half8 val;
#pragma unroll
            for (int e = 0; e < 8; ++e) val[e] = (_Float16)0.f;
            int grow = t0 + krw;
            if (grow < FDIM)
                val = *(const half8*)(KPg + (size_t)grow * 64 + gg * 8);
            *(half8*)(Klds + krw * 64 + ((gg ^ (krw & 7)) << 3)) = val;
        }
        // ---- stage V^T (1 x 16B granule per thread) ----
        {
            int gk = tid & 7, cc = (tid >> 3) & 15, part = tid >> 7;
            int rb = t0 + gk * 8;
            half8 val;
#pragma unroll
            for (int e = 0; e < 8; ++e) val[e] = (_Float16)0.f;
            if (rb < FDIM) {
                val = *(const half8*)(VTg + ((size_t)(part * 16 + cc)) * 520 + rb);
                if (rb + 8 > FDIM) {                 // straddle: zero tail
#pragma unroll
                    for (int e = 0; e < 8; ++e) if (rb + e >= FDIM) val[e] = (_Float16)0.f;
                }
            }
            *(half8*)(VTlds + (part * 16 + cc) * 72 + gk * 8) = val;
        }
        __syncthreads();

        // ---- 4 sub-tiles of 16 keys; each fragment read feeds BOTH q-sets ----
#pragma unroll
        for (int sub = 0; sub < 4; ++sub) {
            const int arow = sub * 16 + qlane;       // K-row supplied by this lane
            const int rx   = arow & 7;
            const _Float16* kr = Klds + arow * 64;
#define KFRAG(h) (*(const half4*)(kr + (((((h) >> 3)) ^ rx) << 3) + ((h) & 7)))
            half4 wh0 = KFRAG(4 * g);
            half4 wh1 = KFRAG(16 + 4 * g);
            half4 wl0 = KFRAG(32 + 4 * g);
            half4 wl1 = KFRAG(48 + 4 * g);
#undef KFRAG
            const int voff = sub * 16 + 4 * g;
            half4 vfr = *(const half4*)(VTlds + qlane * 72 + voff);
            half4 vfi = *(const half4*)(VTlds + (16 + qlane) * 72 + voff);

#pragma unroll
            for (int s = 0; s < 2; ++s) {
                f32x4 sre = {0.f, 0.f, 0.f, 0.f};
                f32x4 sim = {0.f, 0.f, 0.f, 0.f};
                sre = MFMA16(wh0, uh[s][0], sre);
                sre = MFMA16(wh1, uh[s][1], sre);
                sre = MFMA16(wl0, uh[s][0], sre);
                sre = MFMA16(wl1, uh[s][1], sre);
                sre = MFMA16(wh0, ul[s][0], sre);
                sre = MFMA16(wh1, ul[s][1], sre);
                sre = MFMA16(wl0, ul[s][0], sre);    // ll term
                sre = MFMA16(wl1, ul[s][1], sre);
                sim = MFMA16(wh0, u2h[s][0], sim);
                sim = MFMA16(wh1, u2h[s][1], sim);
                sim = MFMA16(wl0, u2h[s][0], sim);
                sim = MFMA16(wl1, u2h[s][1], sim);
                sim = MFMA16(wh0, u2l[s][0], sim);
                sim = MFMA16(wh1, u2l[s][1], sim);
                sim = MFMA16(wl0, u2l[s][0], sim);
                sim = MFMA16(wl1, u2l[s][1], sim);

                float s0 = sqrtf(fmaf(sre[0], sre[0], sim[0] * sim[0]));
                float s1 = sqrtf(fmaf(sre[1], sre[1], sim[1] * sim[1]));
                float s2 = sqrtf(fmaf(sre[2], sre[2], sim[2] * sim[2]));
                float s3 = sqrtf(fmaf(sre[3], sre[3], sim[3] * sim[3]));
                float tmax = fmaxf(fmaxf(s0, s1), fmaxf(s2, s3));
                tmax = fmaxf(tmax, __shfl_xor(tmax, 16));
                tmax = fmaxf(tmax, __shfl_xor(tmax, 32));
                float mnew  = fmaxf(m[s], tmax);
                float alpha = __expf(m[s] - mnew);   // exp(-inf)=0 covers first tile
                m[s] = mnew;
                l[s] *= alpha;
                o_re[s] *= alpha;
                o_im[s] *= alpha;
                float p0 = __expf(s0 - m[s]);
                float p1 = __expf(s1 - m[s]);
                float p2 = __expf(s2 - m[s]);
                float p3 = __expf(s3 - m[s]);
                l[s] += (p0 + p1) + (p2 + p3);
                half4 pk;
                pk[0] = (_Float16)p0; pk[1] = (_Float16)p1;
                pk[2] = (_Float16)p2; pk[3] = (_Float16)p3;
                o_re[s] = MFMA16(vfr, pk, o_re[s]);
                o_im[s] = MFMA16(vfi, pk, o_im[s]);
            }
        }
    }

    // ---- per-set: merge l across the 4 k-groups, normalize, write ----
#pragma unroll
    for (int s = 0; s < 2; ++s) {
        float lt = l[s];
        lt += __shfl_xor(lt, 16);
        lt += __shfl_xor(lt, 32);
        if (frow_s[s] < FDIM) {
            float inv = 1.f / lt;
#pragma unroll
            for (int j = 0; j < 4; ++j) {
                int c = 4 * g + j;                   // D row = channel
                if (c < CDIM)
                    outspec[((size_t)(bg * CDIM + c)) * FDIM + frow_s[s]] =
                        make_float2(o_re[s][j] * inv, o_im[s][j] * inv);
            }
        }
    }
}

// ---------------- Kernel 4: two-for-one irfft(1024), radix-4 fused ----------------
__global__ __launch_bounds__(256) void fft_inv2(const float2* __restrict__ spec,
                                                float* __restrict__ out) {
    __shared__ float re[1056], im[1056];
    const int s2 = blockIdx.x;                   // pair 0..1039
    const float2* Y1 = spec + (size_t)(2 * s2) * FDIM;
    const float2* Y2 = Y1 + FDIM;
    for (int t = threadIdx.x; t < 1024; t += 256) {
        float a, b, c, d;
        if (t <= 512) {
            float2 y1 = Y1[t], y2 = Y2[t];
            bool edge = (t == 0) | (t == 512);
            a = y1.x; b = edge ? 0.f : y1.y;
            c = y2.x; d = edge ? 0.f : y2.y;
        } else {
            float2 y1 = Y1[1024 - t], y2 = Y2[1024 - t];
            a = y1.x; b = -y1.y;
            c = y2.x; d = -y2.y;
        }
        unsigned r = bitrev10(t);
        re[IDX(r)] = a - d;
        im[IDX(r)] = b + c;
    }
    __syncthreads();
    for (int s = 0; s < 10; s += 2) {            // fused stage pair (s, s+1), inverse
        const int h   = 1 << s;
        const int g   = threadIdx.x;
        const int grp = g >> s;
        const int pos = g & (h - 1);
        const int i0  = (grp << (s + 2)) + pos;
        const int j0 = IDX(i0), j1 = IDX(i0 + h), j2 = IDX(i0 + 2 * h), j3 = IDX(i0 + 3 * h);
        float w1s, w1c, w2s, w2c;
        __sincosf((float)M_PI * (float)pos / (float)h, &w1s, &w1c);
        __sincosf((float)M_PI * (float)pos / (float)(2 * h), &w2s, &w2c);
        float ar = re[j0], ai = im[j0], br = re[j1], bi = im[j1];
        float cr = re[j2], ci = im[j2], dr = re[j3], di = im[j3];
        float t1;
        t1 = w1c * br - w1s * bi; bi = w1c * bi + w1s * br; br = t1;   // B *= w1
        t1 = w1c * dr - w1s * di; di = w1c * di + w1s * dr; dr = t1;   // D *= w1
        float e0r = ar + br, e0i = ai + bi, e1r = ar - br, e1i = ai - bi;
        float f0r = cr + dr, f0i = ci + di, f1r = cr - dr, f1i = ci - di;
        t1 = w2c * f0r - w2s * f0i; f0i = w2c * f0i + w2s * f0r; f0r = t1;   // *= w2
        // w3 = +i*w2 = (-w2s, w2c)
        t1 = -w2s * f1r - w2c * f1i; f1i = -w2s * f1i + w2c * f1r; f1r = t1; // *= w3
        re[j0] = e0r + f0r; im[j0] = e0i + f0i;
        re[j2] = e0r - f0r; im[j2] = e0i - f0i;
        re[j1] = e1r + f1r; im[j1] = e1i + f1i;
        re[j3] = e1r - f1r; im[j3] = e1i - f1i;
        __syncthreads();
    }
    const float scale = 1.0f / 1024.0f;
    float* o1 = out + (size_t)(2 * s2) * TDIM;
    for (int t = threadIdx.x; t < 1024; t += 256) {
        o1[t]        = re[IDX(t)] * scale;
        o1[TDIM + t] = im[IDX(t)] * scale;
    }
}

extern "C" void kernel_launch(void* const* d_in, const int* in_sizes, int n_in,
                              void* d_out, int out_size, void* d_ws, size_t ws_size,
                              hipStream_t stream) {
    const float* x  = (const float*)d_in[0];
    const float* wq = (const float*)d_in[1];
    const float* wk = (const float*)d_in[2];
    const float* wv = (const float*)d_in[3];
    float* out = (float*)d_out;

    const size_t n = (size_t)NROW * CDIM;        // 1,067,040 complex per buffer
    float2* xf = (float2*)d_ws;                  // x_fft (signal-major), reused as outspec
    float2* q  = xf + n;                         // 8.54 MB
    _Float16* KP = (_Float16*)(q + n);           // NROW*64 halves = 10.51 MB
    _Float16* VT = KP + (size_t)NROW * 64;       // BG*2*16*520 halves = 5.32 MB

    fft_fwd2<<<BG * CDIM / 2, 256, 0, stream>>>(x, xf);
    qkv_kernel<<<BG * NCHUNK, 256, 0, stream>>>(xf, wq, wk, wv, q, KP, VT);
    attn_kernel<<<BG * NPAIR, 256, 0, stream>>>(q, KP, VT, xf /* outspec, aliases xf */);
    fft_inv2<<<BG * CDIM / 2, 256, 0, stream>>>(xf, out);
}

// Round 18
// 157.955 us; speedup vs baseline: 1.1499x; 1.1499x over previous
//
#include <hip/hip_runtime.h>
#include <math.h>

// Problem constants
#define BDIM 4
#define GDIM 40
#define CDIM 13
#define TDIM 1024
#define FDIM 513                 // T/2 + 1
#define BG   (BDIM*GDIM)         // 160
#define NROW (BG*FDIM)           // 82080 rows of [13] complex
#define NCHUNK 9                 // 9*64 = 576 >= 513 q-rows per bg
#define TK 64                    // K rows staged per LDS tile (attn)
#define QW 64                    // f-rows per qkv block

typedef _Float16 half4 __attribute__((ext_vector_type(4)));
typedef _Float16 half8 __attribute__((ext_vector_type(8)));
typedef float    f32x4 __attribute__((ext_vector_type(4)));

#define MFMA16(a, b, c) __builtin_amdgcn_mfma_f32_16x16x16f16((a), (b), (c), 0, 0, 0)

__device__ __forceinline__ unsigned bitrev10(unsigned x) { return __brev(x) >> 22; }

// padded LDS index: breaks stride-4h bank conflicts in the radix-4 rounds
#define IDX(i) ((i) + ((i) >> 5))

// ---------------- Kernel 1: two-for-one rfft(1024), radix-4 fused ----------------
// 256 threads; 5 fused rounds; barriers 10 -> 5. xf signal-major [sig=bg*13+c][f].
// (r14/r15 verified: coalesced writes + radix-4 = others 98.7 -> 83.4 us)
__global__ __launch_bounds__(256) void fft_fwd2(const float* __restrict__ x,
                                                float2* __restrict__ xf) {
    __shared__ float re[1056], im[1056];
    const int s2 = blockIdx.x;                   // pair index, 0..1039
    const int sigA = 2 * s2, sigB = sigA + 1;
    const float* x1 = x + (size_t)sigA * TDIM;
    const float* x2 = x1 + TDIM;
    for (int t = threadIdx.x; t < 1024; t += 256) {
        unsigned r = bitrev10(t);
        re[IDX(r)] = x1[t];
        im[IDX(r)] = x2[t];
    }
    __syncthreads();
    for (int s = 0; s < 10; s += 2) {            // fused stage pair (s, s+1)
        const int h   = 1 << s;
        const int g   = threadIdx.x;             // 256 groups of 4 points
        const int grp = g >> s;
        const int pos = g & (h - 1);
        const int i0  = (grp << (s + 2)) + pos;
        const int j0 = IDX(i0), j1 = IDX(i0 + h), j2 = IDX(i0 + 2 * h), j3 = IDX(i0 + 3 * h);
        float w1s, w1c, w2s, w2c;
        __sincosf(-(float)M_PI * (float)pos / (float)h, &w1s, &w1c);
        __sincosf(-(float)M_PI * (float)pos / (float)(2 * h), &w2s, &w2c);
        float ar = re[j0], ai = im[j0], br = re[j1], bi = im[j1];
        float cr = re[j2], ci = im[j2], dr = re[j3], di = im[j3];
        float t1;
        t1 = w1c * br - w1s * bi; bi = w1c * bi + w1s * br; br = t1;   // B *= w1
        t1 = w1c * dr - w1s * di; di = w1c * di + w1s * dr; dr = t1;   // D *= w1
        float e0r = ar + br, e0i = ai + bi, e1r = ar - br, e1i = ai - bi;
        float f0r = cr + dr, f0i = ci + di, f1r = cr - dr, f1i = ci - di;
        t1 = w2c * f0r - w2s * f0i; f0i = w2c * f0i + w2s * f0r; f0r = t1;   // *= w2
        // w3 = -i*w2 = (w2s, -w2c)
        t1 = w2s * f1r + w2c * f1i; f1i = w2s * f1i - w2c * f1r; f1r = t1;   // *= w3
        re[j0] = e0r + f0r; im[j0] = e0i + f0i;
        re[j2] = e0r - f0r; im[j2] = e0i - f0i;
        re[j1] = e1r + f1r; im[j1] = e1i + f1i;
        re[j3] = e1r - f1r; im[j3] = e1i - f1i;
        __syncthreads();
    }
    for (int f = threadIdx.x; f < FDIM; f += 256) {
        int fr = (1024 - f) & 1023;
        float zr = re[IDX(f)], zi = im[IDX(f)];
        float wr = re[IDX(fr)], wi = im[IDX(fr)];
        xf[(size_t)sigA * FDIM + f] =
            make_float2(0.5f * (zr + wr), 0.5f * (zi - wi));     // coalesced
        xf[(size_t)sigB * FDIM + f] =
            make_float2(0.5f * (zi + wi), 0.5f * (wr - zr));
    }
}

// ---------------- Kernel 2: Q/K/V projections (coalesced both sides, XCD-pinned) ----------------
__global__ __launch_bounds__(256) void qkv_kernel(const float2* __restrict__ xf,
                           const float* __restrict__ wq,
                           const float* __restrict__ wk,
                           const float* __restrict__ wv,
                           float2* __restrict__ q,
                           _Float16* __restrict__ KP,
                           _Float16* __restrict__ VT) {
    __shared__ float2   Xs[QW * CDIM];           // staged xf rows, [row][c]
    __shared__ float    Ws[3 * CDIM * CDIM];     // wq | wk | wv
    __shared__ _Float16 KPs[QW * 72];            // KP tile, padded stride
    __shared__ _Float16 VTs[32 * 72];            // VT tile (pc = part*16+c, j), padded

    const int bg    = blockIdx.x % BG;           // XCD-pinned
    const int ch    = blockIdx.x / BG;
    const int f0    = ch * QW;
    const int nrows = min(QW, FDIM - f0);        // 64, or 1 for ch==8
    const int tid   = threadIdx.x;
    const int nitems = nrows * CDIM;

    for (int idx = tid; idx < nitems; idx += 256) {
        int c   = idx / nrows;
        int row = idx - c * nrows;
        Xs[row * CDIM + c] = xf[((size_t)bg * CDIM + c) * FDIM + f0 + row];
    }
    for (int idx = tid; idx < 3 * 169; idx += 256)
        Ws[idx] = (idx < 169) ? wq[idx] : ((idx < 338) ? wk[idx - 169] : wv[idx - 338]);
    for (int z = tid; z < 6 * QW; z += 256) {    // zero VT pad c-rows
        int rr = z >> 6, jj = z & 63;
        int pc = (rr < 3) ? (13 + rr) : (29 + (rr - 3));
        VTs[pc * 72 + jj] = (_Float16)0.f;
    }
    __syncthreads();

    for (int item = tid; item < nitems; item += 256) {
        int row = item / CDIM;
        int i   = item - row * CDIM;
        const float2* xrow = &Xs[row * CDIM];
        float qr = 0, qi = 0, kr = 0, ki = 0, vr = 0, vi = 0;
#pragma unroll
        for (int c = 0; c < CDIM; ++c) {
            float2 xc = xrow[c];
            float a = Ws[c * CDIM + i];       qr += xc.x * a; qi += xc.y * a;
            float b = Ws[169 + c * CDIM + i]; kr += xc.x * b; ki += xc.y * b;
            float d = Ws[338 + c * CDIM + i]; vr += xc.x * d; vi += xc.y * d;
        }
        q[((size_t)bg * FDIM + f0) * CDIM + item] = make_float2(qr, qi);  // coalesced
        _Float16* kp = KPs + row * 72;
        _Float16 h0 = (_Float16)kr, h1 = (_Float16)ki;
        kp[i]      = h0;
        kp[13 + i] = h1;
        kp[32 + i] = (_Float16)(kr - (float)h0);
        kp[45 + i] = (_Float16)(ki - (float)h1);
        if (i == 12) {   // zero pad halves 26..31 and 58..63
            *(unsigned*)(kp + 26) = 0u; *(unsigned*)(kp + 28) = 0u; *(unsigned*)(kp + 30) = 0u;
            *(unsigned*)(kp + 58) = 0u; *(unsigned*)(kp + 60) = 0u; *(unsigned*)(kp + 62) = 0u;
        }
        VTs[i * 72 + row]        = (_Float16)vr;   // part 0, c = i
        VTs[(16 + i) * 72 + row] = (_Float16)vi;   // part 1
    }
    __syncthreads();

    _Float16* KPg = KP + ((size_t)bg * FDIM + f0) * 64;
    _Float16* VTg = VT + (size_t)bg * 2 * 16 * 520 + f0;
    if (nrows == QW) {
        for (int idx = tid; idx < QW * 8; idx += 256) {        // 512 x 16B
            int row = idx >> 3, gg = idx & 7;
            *(half8*)(KPg + row * 64 + gg * 8) = *(const half8*)(KPs + row * 72 + gg * 8);
        }
        for (int idx = tid; idx < 32 * 8; idx += 256) {        // 256 x 16B
            int pc = idx >> 3, j8 = idx & 7;
            *(half8*)(VTg + pc * 520 + j8 * 8) = *(const half8*)(VTs + pc * 72 + j8 * 8);
        }
    } else {   // tail chunk: nrows == 1 (f == 512)
        for (int idx = tid; idx < nrows * 8; idx += 256) {
            int row = idx >> 3, gg = idx & 7;
            *(half8*)(KPg + row * 64 + gg * 8) = *(const half8*)(KPs + row * 72 + gg * 8);
        }
        if (tid < 32) VTg[tid * 520] = VTs[tid * 72];
    }
}

// ---------------- Kernel 3: MFMA flash attention (r15 exact: 1 q-set, XCD-pinned) ----------------
// REVERTED to the r15 kernel (76.2 us measured) after the 2-q-set arc closed
// negative: r16 (256,4) spilled at the 64-VGPR tier (107us); r17 (256,3) avoided
// the spill (VGPR 76) but crossed the 64-tier -> occupancy 31->20%, 99us. RULE:
// this kernel's state must stay <= 64 VGPR, which caps it at 1 q-set/wave.
// HISTORY (do not re-litigate): k-split neutral (r3/r4); >=5 waves/EU bound ->
// SPILL (r3/r6); no-LDS = 113us (r8); reg prefetch flat (r9/r10); bg-fused -7us
// (r12); 2-q-set slower (r16/r17). XCD pinning: FETCH 68.4->13.3MB, +5us (r15).
// Fingerprint: 76.2us, VGPR 52, MfmaUtil 32, VALUBusy 63, Occ 31, conflicts 4.98M.
__global__ __launch_bounds__(256, 4) void attn_kernel(const float2* __restrict__ q,
                                                      const _Float16* __restrict__ KP,
                                                      const _Float16* __restrict__ VT,
                                                      float2* __restrict__ outspec) {
    __shared__ __align__(16) _Float16 Klds[TK * 64];        // 8 KB, XOR-swizzled 16B granules
    __shared__ __align__(16) _Float16 VTlds[2 * 16 * 72];   // 4.6 KB, c-stride 72 halves

    const int bg    = blockIdx.x % BG;           // XCD-pinned
    const int chunk = blockIdx.x / BG;
    const int tid   = threadIdx.x;
    const int w     = tid >> 6;
    const int lane  = tid & 63;
    const int qlane = lane & 15;
    const int g     = lane >> 4;
    const int frow  = chunk * 64 + w * 16 + qlane;
    const bool writer = (frow < FDIM);
    const int f     = writer ? frow : (FDIM - 1);
    const size_t rowbase = ((size_t)bg * FDIM + f) * CDIM;

    // ---- build Q fragments in registers: u = [qr,-qi], u' = [qi,qr], hi/lo split ----
    half4 uh[2], ul[2], u2h[2], u2l[2];
#pragma unroll
    for (int c01 = 0; c01 < 2; ++c01) {
#pragma unroll
        for (int j = 0; j < 4; ++j) {
            int k = c01 * 16 + 4 * g + j;
            float a = 0.f, b = 0.f;
            if (k < CDIM) {
                float2 t = q[rowbase + k];          a = t.x;  b = t.y;
            } else if (k < 2 * CDIM) {
                float2 t = q[rowbase + (k - CDIM)]; a = -t.y; b = t.x;
            }
            _Float16 ah = (_Float16)a;
            uh[c01][j]  = ah;
            ul[c01][j]  = (_Float16)(a - (float)ah);
            _Float16 bh = (_Float16)b;
            u2h[c01][j] = bh;
            u2l[c01][j] = (_Float16)(b - (float)bh);
        }
    }

    f32x4 o_re = {0.f, 0.f, 0.f, 0.f};
    f32x4 o_im = {0.f, 0.f, 0.f, 0.f};
    float m = -INFINITY, l = 0.f;

    const _Float16* __restrict__ KPg = KP + (size_t)bg * FDIM * 64;
    const _Float16* __restrict__ VTg = VT + (size_t)bg * 2 * 16 * 520;

    for (int t0 = 0; t0 < FDIM; t0 += TK) {          // 9 tiles of 64 K-rows
        __syncthreads();                             // previous tile fully consumed
        // ---- stage K rows (2 x 16B granules per thread, XOR-swizzled placement) ----
#pragma unroll
        for (int hh = 0; hh < 2; ++hh) {
            int gr  = tid + hh * 256;                // 0..511
            int krw = gr >> 3, gg = gr & 7;
            half8 val;
#pragma unroll
            for (int e = 0; e < 8; ++e) val[e] = (_Float16)0.f;
            int grow = t0 + krw;
            if (grow < FDIM)
                val = *(const half8*)(KPg + (size_t)grow * 64 + gg * 8);
            *(half8*)(Klds + krw * 64 + ((gg ^ (krw & 7)) << 3)) = val;
        }
        // ---- stage V^T (1 x 16B granule per thread) ----
        {
            int gk = tid & 7, cc = (tid >> 3) & 15, part = tid >> 7;
            int rb = t0 + gk * 8;
            half8 val;
#pragma unroll
            for (int e = 0; e < 8; ++e) val[e] = (_Float16)0.f;
            if (rb < FDIM) {
                val = *(const half8*)(VTg + ((size_t)(part * 16 + cc)) * 520 + rb);
                if (rb + 8 > FDIM) {                 // straddle: zero tail (keeps 0*p, no NaN)
#pragma unroll
                    for (int e = 0; e < 8; ++e) if (rb + e >= FDIM) val[e] = (_Float16)0.f;
                }
            }
            *(half8*)(VTlds + (part * 16 + cc) * 72 + gk * 8) = val;
        }
        __syncthreads();

        // ---- 4 sub-tiles of 16 keys ----
#pragma unroll
        for (int sub = 0; sub < 4; ++sub) {
            const int arow = sub * 16 + qlane;       // K-row supplied by this lane (A-frag m)
            const int rx   = arow & 7;
            const _Float16* kr = Klds + arow * 64;
#define KFRAG(h) (*(const half4*)(kr + (((((h) >> 3)) ^ rx) << 3) + ((h) & 7)))
            half4 wh0 = KFRAG(4 * g);
            half4 wh1 = KFRAG(16 + 4 * g);
            half4 wl0 = KFRAG(32 + 4 * g);
            half4 wl1 = KFRAG(48 + 4 * g);
#undef KFRAG
            f32x4 sre = {0.f, 0.f, 0.f, 0.f};
            f32x4 sim = {0.f, 0.f, 0.f, 0.f};
            sre = MFMA16(wh0, uh[0], sre);
            sre = MFMA16(wh1, uh[1], sre);
            sre = MFMA16(wl0, uh[0], sre);
            sre = MFMA16(wl1, uh[1], sre);
            sre = MFMA16(wh0, ul[0], sre);
            sre = MFMA16(wh1, ul[1], sre);
            sre = MFMA16(wl0, ul[0], sre);           // ll term: keeps score err at fp32 level
            sre = MFMA16(wl1, ul[1], sre);
            sim = MFMA16(wh0, u2h[0], sim);
            sim = MFMA16(wh1, u2h[1], sim);
            sim = MFMA16(wl0, u2h[0], sim);
            sim = MFMA16(wl1, u2h[1], sim);
            sim = MFMA16(wh0, u2l[0], sim);
            sim = MFMA16(wh1, u2l[1], sim);
            sim = MFMA16(wl0, u2l[0], sim);
            sim = MFMA16(wl1, u2l[1], sim);

            // |score| ; this lane holds scores for its q at kidx = sub*16 + 4g + j
            float s0 = sqrtf(fmaf(sre[0], sre[0], sim[0] * sim[0]));
            float s1 = sqrtf(fmaf(sre[1], sre[1], sim[1] * sim[1]));
            float s2 = sqrtf(fmaf(sre[2], sre[2], sim[2] * sim[2]));
            float s3 = sqrtf(fmaf(sre[3], sre[3], sim[3] * sim[3]));
            float tmax = fmaxf(fmaxf(s0, s1), fmaxf(s2, s3));
            tmax = fmaxf(tmax, __shfl_xor(tmax, 16));
            tmax = fmaxf(tmax, __shfl_xor(tmax, 32));
            float mnew  = fmaxf(m, tmax);
            float alpha = __expf(m - mnew);          // exp(-inf)=0 covers first tile
            m = mnew;
            l *= alpha;
            o_re *= alpha;
            o_im *= alpha;
            float p0 = __expf(s0 - m);
            float p1 = __expf(s1 - m);
            float p2 = __expf(s2 - m);
            float p3 = __expf(s3 - m);
            l += (p0 + p1) + (p2 + p3);
            half4 pk;
            pk[0] = (_Float16)p0; pk[1] = (_Float16)p1;
            pk[2] = (_Float16)p2; pk[3] = (_Float16)p3;

            const int voff = sub * 16 + 4 * g;
            half4 vfr = *(const half4*)(VTlds + qlane * 72 + voff);
            half4 vfi = *(const half4*)(VTlds + (16 + qlane) * 72 + voff);
            o_re = MFMA16(vfr, pk, o_re);
            o_im = MFMA16(vfi, pk, o_im);
        }
    }

    // ---- merge partial l across the 4 k-groups of each q-column ----
    l += __shfl_xor(l, 16);
    l += __shfl_xor(l, 32);
    if (writer) {
        float inv = 1.f / l;
#pragma unroll
        for (int j = 0; j < 4; ++j) {
            int c = 4 * g + j;                       // D row = channel
            if (c < CDIM)
                outspec[((size_t)(bg * CDIM + c)) * FDIM + frow] =
                    make_float2(o_re[j] * inv, o_im[j] * inv);
        }
    }
}

// ---------------- Kernel 4: two-for-one irfft(1024), radix-4 fused ----------------
__global__ __launch_bounds__(256) void fft_inv2(const float2* __restrict__ spec,
                                                float* __restrict__ out) {
    __shared__ float re[1056], im[1056];
    const int s2 = blockIdx.x;                   // pair 0..1039
    const float2* Y1 = spec + (size_t)(2 * s2) * FDIM;
    const float2* Y2 = Y1 + FDIM;
    for (int t = threadIdx.x; t < 1024; t += 256) {
        float a, b, c, d;
        if (t <= 512) {
            float2 y1 = Y1[t], y2 = Y2[t];
            bool edge = (t == 0) | (t == 512);
            a = y1.x; b = edge ? 0.f : y1.y;
            c = y2.x; d = edge ? 0.f : y2.y;
        } else {
            float2 y1 = Y1[1024 - t], y2 = Y2[1024 - t];
            a = y1.x; b = -y1.y;
            c = y2.x; d = -y2.y;
        }
        unsigned r = bitrev10(t);
        re[IDX(r)] = a - d;
        im[IDX(r)] = b + c;
    }
    __syncthreads();
    for (int s = 0; s < 10; s += 2) {            // fused stage pair (s, s+1), inverse
        const int h   = 1 << s;
        const int g   = threadIdx.x;
        const int grp = g >> s;
        const int pos = g & (h - 1);
        const int i0  = (grp << (s + 2)) + pos;
        const int j0 = IDX(i0), j1 = IDX(i0 + h), j2 = IDX(i0 + 2 * h), j3 = IDX(i0 + 3 * h);
        float w1s, w1c, w2s, w2c;
        __sincosf((float)M_PI * (float)pos / (float)h, &w1s, &w1c);
        __sincosf((float)M_PI * (float)pos / (float)(2 * h), &w2s, &w2c);
        float ar = re[j0], ai = im[j0], br = re[j1], bi = im[j1];
        float cr = re[j2], ci = im[j2], dr = re[j3], di = im[j3];
        float t1;
        t1 = w1c * br - w1s * bi; bi = w1c * bi + w1s * br; br = t1;   // B *= w1
        t1 = w1c * dr - w1s * di; di = w1c * di + w1s * dr; dr = t1;   // D *= w1
        float e0r = ar + br, e0i = ai + bi, e1r = ar - br, e1i = ai - bi;
        float f0r = cr + dr, f0i = ci + di, f1r = cr - dr, f1i = ci - di;
        t1 = w2c * f0r - w2s * f0i; f0i = w2c * f0i + w2s * f0r; f0r = t1;   // *= w2
        // w3 = +i*w2 = (-w2s, w2c)
        t1 = -w2s * f1r - w2c * f1i; f1i = -w2s * f1i + w2c * f1r; f1r = t1; // *= w3
        re[j0] = e0r + f0r; im[j0] = e0i + f0i;
        re[j2] = e0r - f0r; im[j2] = e0i - f0i;
        re[j1] = e1r + f1r; im[j1] = e1i + f1i;
        re[j3] = e1r - f1r; im[j3] = e1i - f1i;
        __syncthreads();
    }
    const float scale = 1.0f / 1024.0f;
    float* o1 = out + (size_t)(2 * s2) * TDIM;
    for (int t = threadIdx.x; t < 1024; t += 256) {
        o1[t]        = re[IDX(t)] * scale;
        o1[TDIM + t] = im[IDX(t)] * scale;
    }
}

extern "C" void kernel_launch(void* const* d_in, const int* in_sizes, int n_in,
                              void* d_out, int out_size, void* d_ws, size_t ws_size,
                              hipStream_t stream) {
    const float* x  = (const float*)d_in[0];
    const float* wq = (const float*)d_in[1];
    const float* wk = (const float*)d_in[2];
    const float* wv = (const float*)d_in[3];
    float* out = (float*)d_out;

    const size_t n = (size_t)NROW * CDIM;        // 1,067,040 complex per buffer
    float2* xf = (float2*)d_ws;                  // x_fft (signal-major), reused as outspec
    float2* q  = xf + n;                         // 8.54 MB
    _Float16* KP = (_Float16*)(q + n);           // NROW*64 halves = 10.51 MB
    _Float16* VT = KP + (size_t)NROW * 64;       // BG*2*16*520 halves = 5.32 MB

    fft_fwd2<<<BG * CDIM / 2, 256, 0, stream>>>(x, xf);
    qkv_kernel<<<BG * NCHUNK, 256, 0, stream>>>(xf, wq, wk, wv, q, KP, VT);
    attn_kernel<<<BG * NCHUNK, 256, 0, stream>>>(q, KP, VT, xf /* outspec, aliases xf */);
    fft_inv2<<<BG * CDIM / 2, 256, 0, stream>>>(xf, out);
}